// Round 2
// baseline (120.658 us; speedup 1.0000x reference)
//
#include <hip/hip_runtime.h>

constexpr int Wd = 512;
constexpr int PLANE = 512 * 512;

// ---------------- kernel 1: per-plane-segment min/max partials ----------------
__global__ __launch_bounds__(256) void minmax_part(const float* __restrict__ pred,
                                                   const float* __restrict__ targ,
                                                   float* __restrict__ pmx,
                                                   float* __restrict__ pmn) {
    int bx = blockIdx.x;
    int plane = bx >> 3, seg = bx & 7;
    size_t base = (size_t)plane * PLANE + (size_t)seg * 32768;
    const float4* p4 = reinterpret_cast<const float4*>(pred + base);
    const float4* t4 = reinterpret_cast<const float4*>(targ + base);
    float mx = -3.0e38f, mn = 3.0e38f;
    for (int i = threadIdx.x; i < 8192; i += 256) {
        float4 a = p4[i], b = t4[i];
        mx = fmaxf(mx, fmaxf(fmaxf(fmaxf(a.x, b.x), fmaxf(a.y, b.y)),
                             fmaxf(fmaxf(a.z, b.z), fmaxf(a.w, b.w))));
        mn = fminf(mn, fminf(fminf(fminf(a.x, b.x), fminf(a.y, b.y)),
                             fminf(fminf(a.z, b.z), fminf(a.w, b.w))));
    }
    #pragma unroll
    for (int off = 32; off; off >>= 1) {
        mx = fmaxf(mx, __shfl_down(mx, off));
        mn = fminf(mn, __shfl_down(mn, off));
    }
    __shared__ float smx[4], smn[4];
    int wid = threadIdx.x >> 6, lane = threadIdx.x & 63;
    if (lane == 0) { smx[wid] = mx; smn[wid] = mn; }
    __syncthreads();
    if (threadIdx.x == 0) {
        pmx[bx] = fmaxf(fmaxf(smx[0], smx[1]), fmaxf(smx[2], smx[3]));
        pmn[bx] = fminf(fminf(smn[0], smn[1]), fminf(smn[2], smn[3]));
    }
}

// ---------------- kernel 2: finalize c1/c2 per plane ----------------
__global__ void minmax_fin(const float* __restrict__ pmx, const float* __restrict__ pmn,
                           float* __restrict__ c1s, float* __restrict__ c2s, int planes) {
    int p = blockIdx.x * blockDim.x + threadIdx.x;
    if (p < planes) {
        float mx = -3.0e38f, mn = 3.0e38f;
        for (int s = 0; s < 8; ++s) {
            mx = fmaxf(mx, pmx[p * 8 + s]);
            mn = fminf(mn, pmn[p * 8 + s]);
        }
        float dr = fmaxf(mx - mn, 1e-6f);
        float a = 0.01f * dr, b = 0.03f * dr;
        c1s[p] = a * a;
        c2s[p] = b * b;
    }
}

// ---------------- kernel 3: fused separable SSIM, shuffle-based ----------------
// Grid: planes*8 blocks x 256 threads = 4 independent waves. Each wave owns 16
// output rows; lane c owns columns 8c..8c+7. Vertical 11-row running box sums
// of {p,t,pp,tt,pt} in registers. Horizontal 11-col box sum done entirely with
// per-lane prefix sums + neighbor-lane __shfl (no LDS, no barriers).
__global__ __launch_bounds__(256) void ssim_main(const float* __restrict__ pred,
                                                 const float* __restrict__ targ,
                                                 const float* __restrict__ c1s,
                                                 const float* __restrict__ c2s,
                                                 float* __restrict__ parts) {
    __shared__ float red[4];
    int bx = blockIdx.x;
    int plane = bx >> 3, tile = bx & 7;
    int wid = threadIdx.x >> 6, c = threadIdx.x & 63;
    const float c1 = c1s[plane], c2 = c2s[plane];
    const float* Pg = pred + (size_t)plane * PLANE;
    const float* Tg = targ + (size_t)plane * PLANE;
    int r0 = tile * 64 + wid * 16;  // first output row of this wave
    const bool lane0 = (c == 0), lane63 = (c == 63);

    float vsP[8], vsT[8], vsPP[8], vsTT[8], vsPT[8];
    #pragma unroll
    for (int k = 0; k < 8; ++k) { vsP[k] = 0; vsT[k] = 0; vsPP[k] = 0; vsTT[k] = 0; vsPT[k] = 0; }

    auto acc = [&](int r, float s) {
        if ((unsigned)r < 512u) {
            const float4* prow = reinterpret_cast<const float4*>(Pg + (size_t)r * Wd);
            const float4* trow = reinterpret_cast<const float4*>(Tg + (size_t)r * Wd);
            float4 a0 = prow[2 * c], a1 = prow[2 * c + 1];
            float4 b0 = trow[2 * c], b1 = trow[2 * c + 1];
            float pa[8] = {a0.x, a0.y, a0.z, a0.w, a1.x, a1.y, a1.z, a1.w};
            float tb[8] = {b0.x, b0.y, b0.z, b0.w, b1.x, b1.y, b1.z, b1.w};
            #pragma unroll
            for (int k = 0; k < 8; ++k) {
                float sp = s * pa[k], st = s * tb[k];
                vsP[k]  += sp;
                vsT[k]  += st;
                vsPP[k] += sp * pa[k];
                vsTT[k] += st * tb[k];
                vsPT[k] += sp * tb[k];
            }
        }
    };

    // Horizontal 11-tap box sum over this lane's 8 columns using neighbor shfl.
    auto hsum = [&](const float v[8], float H[8]) {
        float P[8];
        P[0] = v[0];
        #pragma unroll
        for (int k = 1; k < 8; ++k) P[k] = P[k - 1] + v[k];
        float T = P[7];
        float Tm  = __shfl_up(T, 1);
        float Pm2 = __shfl_up(P[2], 1);
        float Pm3 = __shfl_up(P[3], 1);
        float Pm4 = __shfl_up(P[4], 1);
        float Pm5 = __shfl_up(P[5], 1);
        float Pm6 = __shfl_up(P[6], 1);
        if (lane0) { Tm = 0; Pm2 = 0; Pm3 = 0; Pm4 = 0; Pm5 = 0; Pm6 = 0; }
        float Pp0 = __shfl_down(P[0], 1);
        float Pp1 = __shfl_down(P[1], 1);
        float Pp2 = __shfl_down(P[2], 1);
        float Pp3 = __shfl_down(P[3], 1);
        float Pp4 = __shfl_down(P[4], 1);
        if (lane63) { Pp0 = 0; Pp1 = 0; Pp2 = 0; Pp3 = 0; Pp4 = 0; }
        H[0] = (Tm - Pm2) + P[5];
        H[1] = (Tm - Pm3) + P[6];
        H[2] = (Tm - Pm4) + T;
        H[3] = (Tm - Pm5) + (T + Pp0);
        H[4] = (Tm - Pm6) + (T + Pp1);
        H[5] = T + Pp2;
        H[6] = (T - P[0]) + Pp3;
        H[7] = (T - P[1]) + Pp4;
    };

    // init vertical window: rows r0-5 .. r0+4
    for (int r = r0 - 5; r <= r0 + 4; ++r) acc(r, 1.0f);

    float lsum = 0.0f;
    #pragma unroll 1
    for (int it = 0; it < 16; ++it) {
        int orow = r0 + it;
        acc(orow + 5, 1.0f);  // window now rows orow-5..orow+5

        float H[5][8];
        hsum(vsP,  H[0]);
        hsum(vsT,  H[1]);
        hsum(vsPP, H[2]);
        hsum(vsTT, H[3]);
        hsum(vsPT, H[4]);

        constexpr float inv = 1.0f / 121.0f;
        #pragma unroll
        for (int i = 0; i < 8; ++i) {
            float mup = H[0][i] * inv, mut = H[1][i] * inv;
            float spp = fmaxf(H[2][i] * inv - mup * mup, 0.0f);
            float stt = fmaxf(H[3][i] * inv - mut * mut, 0.0f);
            float spt = H[4][i] * inv - mup * mut;
            float num = (2.0f * mup * mut + c1) * (2.0f * spt + c2);
            float den = (mup * mup + mut * mut + c1) * (spp + stt + c2);
            float ssim = __fdividef(num, den + 1e-6f);
            lsum += fmaxf((1.0f - ssim) * 0.5f, 0.0f);
        }
        acc(orow - 5, -1.0f);  // drop top row of window
    }

    #pragma unroll
    for (int off = 32; off; off >>= 1) lsum += __shfl_down(lsum, off);
    if (c == 0) red[wid] = lsum;
    __syncthreads();
    if (threadIdx.x == 0) parts[bx] = (red[0] + red[1]) + (red[2] + red[3]);
}

// ---------------- kernel 4: deterministic final reduce ----------------
__global__ void finish(const float* __restrict__ parts, float* __restrict__ out,
                       int n, float invN) {
    float s = 0.0f;
    for (int i = threadIdx.x; i < n; i += 256) s += parts[i];
    #pragma unroll
    for (int off = 32; off; off >>= 1) s += __shfl_down(s, off);
    __shared__ float sw[4];
    int wid = threadIdx.x >> 6, lane = threadIdx.x & 63;
    if (lane == 0) sw[wid] = s;
    __syncthreads();
    if (threadIdx.x == 0) out[0] = ((sw[0] + sw[1]) + (sw[2] + sw[3])) * invN;
}

extern "C" void kernel_launch(void* const* d_in, const int* in_sizes, int n_in,
                              void* d_out, int out_size, void* d_ws, size_t ws_size,
                              hipStream_t stream) {
    const float* pred = (const float*)d_in[0];
    const float* targ = (const float*)d_in[1];
    float* out = (float*)d_out;
    int planes = in_sizes[0] / PLANE;  // 96
    int G = planes * 8;                // 768 blocks

    float* ws   = (float*)d_ws;
    float* pmx  = ws;                  // G
    float* pmn  = ws + G;              // G
    float* c1s  = ws + 2 * G;          // planes
    float* c2s  = ws + 2 * G + planes; // planes
    float* prts = ws + 2 * G + 2 * planes;  // G

    minmax_part<<<G, 256, 0, stream>>>(pred, targ, pmx, pmn);
    minmax_fin<<<(planes + 127) / 128, 128, 0, stream>>>(pmx, pmn, c1s, c2s, planes);
    ssim_main<<<G, 256, 0, stream>>>(pred, targ, c1s, c2s, prts);
    float invN = 1.0f / ((float)planes * (float)PLANE);
    finish<<<1, 256, 0, stream>>>(prts, out, G, invN);
}